// Round 2
// baseline (82.569 us; speedup 1.0000x reference)
//
#include <hip/hip_runtime.h>
#include <math.h>

#define KC 3
#define NF 8
#define HH 480
#define WW 640
#define HWPIX (HH * WW)

__global__ __launch_bounds__(256) void gmm_fit_process_kernel(
    const float* __restrict__ frames,   // [N,H,W,3]
    const float* __restrict__ frame,    // [H,W,3]
    const int* __restrict__ n_iter_p,
    float* __restrict__ out)            // [2,H,W]
{
    const int p = blockIdx.x * blockDim.x + threadIdx.x;
    if (p >= HWPIX) return;
    const int n_iter = *n_iter_p;

    // ---- load the N=8 samples for this pixel into registers ----
    float X[NF][3];
#pragma unroll
    for (int n = 0; n < NF; ++n) {
        const float* src = frames + (size_t)n * (HWPIX * 3) + (size_t)p * 3;
        X[n][0] = src[0];
        X[n][1] = src[1];
        X[n][2] = src[2];
    }

    // ---- init GMM state (matches reference init) ----
    float mean[KC][3], dev[KC], weight[KC];
#pragma unroll
    for (int k = 0; k < KC; ++k) {
        const float m0 = (float)(k + 1) / 4.0f;
        mean[k][0] = m0; mean[k][1] = m0; mean[k][2] = m0;
        dev[k] = 1.0f;
        weight[k] = 1.0f / 3.0f;
    }

    const float NORMC = 15.749609945722419f;  // sqrt((2*pi)^3)
    const float DEV_FLOOR = 1e-30f;           // guard: no-op unless dev underflows

    // ---- EM iterations ----
    for (int it = 0; it < n_iter; ++it) {
        float R[NF][KC];
        // E-step: responsibilities
#pragma unroll
        for (int n = 0; n < NF; ++n) {
            float s = 0.0f;
#pragma unroll
            for (int k = 0; k < KC; ++k) {
                const float dsafe = fmaxf(dev[k], DEV_FLOOR);
                const float dx = X[n][0] - mean[k][0];
                const float dy = X[n][1] - mean[k][1];
                const float dz = X[n][2] - mean[k][2];
                const float d2 = dx * dx + dy * dy + dz * dz;
                // match jnp order: 2.0 * square(dev)
                const float P = expf(-d2 / (2.0f * (dsafe * dsafe))) / (NORMC * dsafe);
                const float r = weight[k] * P;
                R[n][k] = r;
                s += r;
            }
            // guard: if all components starved (s==0), leave R at 0
            const float sinv = (s > 0.0f) ? (1.0f / s) : 0.0f;
#pragma unroll
            for (int k = 0; k < KC; ++k) R[n][k] = (s > 0.0f) ? (R[n][k] / s) : 0.0f;
            (void)sinv;
        }

        // M-step
#pragma unroll
        for (int k = 0; k < KC; ++k) {
            float rs = 0.0f, mx = 0.0f, my = 0.0f, mz = 0.0f;
#pragma unroll
            for (int n = 0; n < NF; ++n) {
                const float r = R[n][k];
                rs += r;
                mx += r * X[n][0];
                my += r * X[n][1];
                mz += r * X[n][2];
            }
            if (rs > 0.0f) {
                const float m0 = mx / rs, m1 = my / rs, m2 = mz / rs;
                float acc = 0.0f;
#pragma unroll
                for (int n = 0; n < NF; ++n) {
                    const float dx = X[n][0] - m0;
                    const float dy = X[n][1] - m1;
                    const float dz = X[n][2] - m2;
                    acc += R[n][k] * (dx * dx + dy * dy + dz * dz);
                }
                weight[k] = rs / (float)NF;
                mean[k][0] = m0; mean[k][1] = m1; mean[k][2] = m2;
                dev[k] = acc / rs;   // mean squared distance (never sqrt'd) — as ref
            } else {
                // starved component: keep previous mean/dev, weight = 0 (== rs/N)
                weight[k] = 0.0f;
            }
        }
    }

    // ---- fg mask: ratio <= min(ratio) ----
    float ratio[KC];
    float rmin = 3.402823466e+38f;
#pragma unroll
    for (int k = 0; k < KC; ++k) {
        ratio[k] = weight[k] / fmaxf(dev[k], DEV_FLOOR);
        rmin = fminf(rmin, ratio[k]);
    }
    bool fg[KC];
#pragma unroll
    for (int k = 0; k < KC; ++k) fg[k] = (ratio[k] <= rmin);

    // ---- process the single test frame ----
    const float fx = frame[(size_t)p * 3 + 0];
    const float fy = frame[(size_t)p * 3 + 1];
    const float fz = frame[(size_t)p * 3 + 2];

    float mind = 3.402823466e+38f;
    int index = 0;
#pragma unroll
    for (int k = 0; k < KC; ++k) {
        const float dx = fx - mean[k][0];
        const float dy = fy - mean[k][1];
        const float dz = fz - mean[k][2];
        const float dist = sqrtf(dx * dx + dy * dy + dz * dz);
        if (dist < mind) {  // first-minimum semantics of jnp.argmin
            mind = dist;
            index = k;
        }
    }

    float mask = fg[index] ? 255.0f : 0.0f;
    if (!isfinite(mind)) mind = 0.0f;  // last-resort finiteness guard

    out[p] = mask;
    out[HWPIX + p] = mind;
}

extern "C" void kernel_launch(void* const* d_in, const int* in_sizes, int n_in,
                              void* d_out, int out_size, void* d_ws, size_t ws_size,
                              hipStream_t stream) {
    const float* frames = (const float*)d_in[0];
    const float* frame  = (const float*)d_in[1];
    const int*   n_iter = (const int*)d_in[2];
    float* out = (float*)d_out;

    const int threads = 256;
    const int blocks = (HWPIX + threads - 1) / threads;
    gmm_fit_process_kernel<<<blocks, threads, 0, stream>>>(frames, frame, n_iter, out);
}

// Round 3
// 31.735 us; speedup vs baseline: 2.6018x; 2.6018x over previous
//
#include <hip/hip_runtime.h>
#include <math.h>

#define KC 3
#define NF 8
#define HH 480
#define WW 640
#define HWPIX (HH * WW)

__device__ __forceinline__ float frcp(float x) { return __builtin_amdgcn_rcpf(x); }

__global__ __launch_bounds__(256) void gmm_fit_process_kernel(
    const float* __restrict__ frames,   // [N,H,W,3]
    const float* __restrict__ frame,    // [H,W,3]
    const int* __restrict__ n_iter_p,
    float* __restrict__ out)            // [2,H,W]
{
    const int p = blockIdx.x * blockDim.x + threadIdx.x;
    if (p >= HWPIX) return;
    const int n_iter = *n_iter_p;

    // ---- load the N=8 samples for this pixel into registers ----
    float X[NF][3];
    float X2[NF];  // ||X||^2, hoisted for the Koenig variance identity
#pragma unroll
    for (int n = 0; n < NF; ++n) {
        const float* src = frames + (size_t)n * (HWPIX * 3) + (size_t)p * 3;
        X[n][0] = src[0];
        X[n][1] = src[1];
        X[n][2] = src[2];
        X2[n] = X[n][0] * X[n][0] + X[n][1] * X[n][1] + X[n][2] * X[n][2];
    }

    // ---- init GMM state (matches reference init) ----
    float mean[KC][3], dev[KC], weight[KC];
#pragma unroll
    for (int k = 0; k < KC; ++k) {
        const float m0 = (float)(k + 1) / 4.0f;
        mean[k][0] = m0; mean[k][1] = m0; mean[k][2] = m0;
        dev[k] = 1.0f;
        weight[k] = 1.0f / 3.0f;
    }

    const float INV_NORM = 0.06349363593424097f;  // 1/sqrt((2*pi)^3)
    const float DEV_FLOOR = 1e-12f;
    const float S_FLOOR = 1e-20f;

    // ---- EM iterations ----
    for (int it = 0; it < n_iter; ++it) {
        // hoist per-component constants: 3 rcp per iteration total
        float a[KC], c[KC];
#pragma unroll
        for (int k = 0; k < KC; ++k) {
            const float dsafe = fmaxf(dev[k], DEV_FLOOR);
            const float invd = frcp(dsafe);
            a[k] = -0.5f * invd * invd;          // exponent scale
            c[k] = weight[k] * INV_NORM * invd;  // prefactor (weight folded in)
        }

        float R[NF][KC];
#pragma unroll
        for (int n = 0; n < NF; ++n) {
            float s = 0.0f;
#pragma unroll
            for (int k = 0; k < KC; ++k) {
                const float dx = X[n][0] - mean[k][0];
                const float dy = X[n][1] - mean[k][1];
                const float dz = X[n][2] - mean[k][2];
                const float d2 = dx * dx + dy * dy + dz * dz;
                const float r = c[k] * __expf(a[k] * d2);
                R[n][k] = r;
                s += r;
            }
            // guard: if all components starved, leave R at 0
            const float sinv = (s > S_FLOOR) ? frcp(s) : 0.0f;
#pragma unroll
            for (int k = 0; k < KC; ++k) R[n][k] *= sinv;
        }

        // M-step
#pragma unroll
        for (int k = 0; k < KC; ++k) {
            float rs = 0.0f, mx = 0.0f, my = 0.0f, mz = 0.0f, acc2 = 0.0f;
#pragma unroll
            for (int n = 0; n < NF; ++n) {
                const float r = R[n][k];
                rs += r;
                mx += r * X[n][0];
                my += r * X[n][1];
                mz += r * X[n][2];
                acc2 += r * X2[n];
            }
            if (rs > S_FLOOR) {
                const float invrs = frcp(rs);
                const float m0 = mx * invrs, m1 = my * invrs, m2c = mz * invrs;
                const float m2 = m0 * m0 + m1 * m1 + m2c * m2c;
                weight[k] = rs * (1.0f / (float)NF);
                mean[k][0] = m0; mean[k][1] = m1; mean[k][2] = m2c;
                // Koenig: E_R[||X-m||^2] = (sum R*||X||^2)/rs - ||m||^2
                dev[k] = acc2 * invrs - m2;
            } else {
                // starved component: keep previous mean/dev, weight = 0
                weight[k] = 0.0f;
            }
        }
    }

    // ---- fg mask: ratio <= min(ratio) ----
    float ratio[KC];
    float rmin = 3.402823466e+38f;
#pragma unroll
    for (int k = 0; k < KC; ++k) {
        ratio[k] = weight[k] * frcp(fmaxf(dev[k], DEV_FLOOR));
        rmin = fminf(rmin, ratio[k]);
    }
    bool fg[KC];
#pragma unroll
    for (int k = 0; k < KC; ++k) fg[k] = (ratio[k] <= rmin);

    // ---- process the single test frame ----
    const float fx = frame[(size_t)p * 3 + 0];
    const float fy = frame[(size_t)p * 3 + 1];
    const float fz = frame[(size_t)p * 3 + 2];

    float mind = 3.402823466e+38f;
    int index = 0;
#pragma unroll
    for (int k = 0; k < KC; ++k) {
        const float dx = fx - mean[k][0];
        const float dy = fy - mean[k][1];
        const float dz = fz - mean[k][2];
        const float dist = __builtin_amdgcn_sqrtf(dx * dx + dy * dy + dz * dz);
        if (dist < mind) {  // first-minimum semantics of jnp.argmin
            mind = dist;
            index = k;
        }
    }

    float mask = fg[index] ? 255.0f : 0.0f;
    if (!isfinite(mind)) mind = 0.0f;  // last-resort finiteness guard

    out[p] = mask;
    out[HWPIX + p] = mind;
}

extern "C" void kernel_launch(void* const* d_in, const int* in_sizes, int n_in,
                              void* d_out, int out_size, void* d_ws, size_t ws_size,
                              hipStream_t stream) {
    const float* frames = (const float*)d_in[0];
    const float* frame  = (const float*)d_in[1];
    const int*   n_iter = (const int*)d_in[2];
    float* out = (float*)d_out;

    const int threads = 256;
    const int blocks = (HWPIX + threads - 1) / threads;
    gmm_fit_process_kernel<<<blocks, threads, 0, stream>>>(frames, frame, n_iter, out);
}

// Round 4
// 29.730 us; speedup vs baseline: 2.7773x; 1.0675x over previous
//
#include <hip/hip_runtime.h>
#include <math.h>

#define KC 3
#define NF 8
#define HH 480
#define WW 640
#define HWPIX (HH * WW)

__device__ __forceinline__ float frcp(float x) { return __builtin_amdgcn_rcpf(x); }
__device__ __forceinline__ float fexp2(float x) { return __builtin_amdgcn_exp2f(x); }

__global__ __launch_bounds__(64) void gmm_fit_process_kernel(
    const float* __restrict__ frames,   // [N,H,W,3]
    const float* __restrict__ frame,    // [H,W,3]
    const int* __restrict__ n_iter_p,
    float* __restrict__ out)            // [2,H,W]
{
    const int p = blockIdx.x * blockDim.x + threadIdx.x;
    if (p >= HWPIX) return;
    const int n_iter = *n_iter_p;

    // ---- load the N=8 samples for this pixel into registers ----
    float X[NF][3];
    float X2[NF];  // ||X||^2 (hoisted; feeds both exponent and Koenig variance)
#pragma unroll
    for (int n = 0; n < NF; ++n) {
        const float* src = frames + (size_t)n * (HWPIX * 3) + (size_t)p * 3;
        X[n][0] = src[0];
        X[n][1] = src[1];
        X[n][2] = src[2];
        X2[n] = X[n][0] * X[n][0] + X[n][1] * X[n][1] + X[n][2] * X[n][2];
    }

    // ---- init GMM state (matches reference init) ----
    float mean[KC][3], dev[KC], weight[KC];
#pragma unroll
    for (int k = 0; k < KC; ++k) {
        const float m0 = (float)(k + 1) / 4.0f;
        mean[k][0] = m0; mean[k][1] = m0; mean[k][2] = m0;
        dev[k] = 1.0f;
        weight[k] = 1.0f / 3.0f;
    }

    const float INV_NORM = 0.06349363593424097f;  // 1/sqrt((2*pi)^3)
    const float L2E = 1.4426950408889634f;        // log2(e)
    const float DEV_FLOOR = 1e-12f;
    const float S_FLOOR = 1e-20f;

    // ---- EM iterations ----
    for (int it = 0; it < n_iter; ++it) {
        // Per-component constants (3 rcp / iter total).
        // exponent (base-2): e = A[k]*X2[n] + B[k] + C[k]*dot(mean[k], X[n])
        //   where a2 = -0.5*invd^2*log2(e); A=a2, B=a2*||m||^2, C=-2*a2
        float A[KC], B[KC], C[KC], c[KC];
#pragma unroll
        for (int k = 0; k < KC; ++k) {
            const float dsafe = fmaxf(dev[k], DEV_FLOOR);
            const float invd = frcp(dsafe);
            const float a2 = -0.5f * L2E * invd * invd;
            const float m2 = mean[k][0] * mean[k][0] + mean[k][1] * mean[k][1]
                           + mean[k][2] * mean[k][2];
            A[k] = a2;
            B[k] = a2 * m2;
            C[k] = -2.0f * a2;
            c[k] = weight[k] * INV_NORM * invd;
        }

        // Fused E+M accumulation: one pass over samples, no R array.
        float rs[KC], mx[KC], my[KC], mz[KC], acc2[KC];
#pragma unroll
        for (int k = 0; k < KC; ++k) { rs[k] = mx[k] = my[k] = mz[k] = acc2[k] = 0.0f; }

#pragma unroll
        for (int n = 0; n < NF; ++n) {
            float r[KC], s = 0.0f;
#pragma unroll
            for (int k = 0; k < KC; ++k) {
                const float t = mean[k][0] * X[n][0]
                              + mean[k][1] * X[n][1]
                              + mean[k][2] * X[n][2];
                float e = A[k] * X2[n] + B[k];
                e = C[k] * t + e;
                r[k] = c[k] * fexp2(e);
                s += r[k];
            }
            const float sinv = (s > S_FLOOR) ? frcp(s) : 0.0f;
#pragma unroll
            for (int k = 0; k < KC; ++k) {
                const float rk = r[k] * sinv;
                rs[k] += rk;
                mx[k] += rk * X[n][0];
                my[k] += rk * X[n][1];
                mz[k] += rk * X[n][2];
                acc2[k] += rk * X2[n];
            }
        }

        // M-step finalize
#pragma unroll
        for (int k = 0; k < KC; ++k) {
            if (rs[k] > S_FLOOR) {
                const float invrs = frcp(rs[k]);
                const float m0 = mx[k] * invrs, m1 = my[k] * invrs, m2c = mz[k] * invrs;
                const float mm2 = m0 * m0 + m1 * m1 + m2c * m2c;
                weight[k] = rs[k] * (1.0f / (float)NF);
                mean[k][0] = m0; mean[k][1] = m1; mean[k][2] = m2c;
                // Koenig: E_R[||X-m||^2] = (sum R*||X||^2)/rs - ||m||^2
                // (can go slightly negative by cancellation; fmax guards at uses)
                dev[k] = acc2[k] * invrs - mm2;
            } else {
                weight[k] = 0.0f;  // starved: keep mean/dev, weight = rs/N = 0
            }
        }
    }

    // ---- fg mask: ratio <= min(ratio) ----
    float ratio[KC];
    float rmin = 3.402823466e+38f;
#pragma unroll
    for (int k = 0; k < KC; ++k) {
        ratio[k] = weight[k] * frcp(fmaxf(dev[k], DEV_FLOOR));
        rmin = fminf(rmin, ratio[k]);
    }

    // ---- process the single test frame ----
    const float fx = frame[(size_t)p * 3 + 0];
    const float fy = frame[(size_t)p * 3 + 1];
    const float fz = frame[(size_t)p * 3 + 2];

    float mind = 3.402823466e+38f;
    int index = 0;
#pragma unroll
    for (int k = 0; k < KC; ++k) {
        const float dx = fx - mean[k][0];
        const float dy = fy - mean[k][1];
        const float dz = fz - mean[k][2];
        const float dist = __builtin_amdgcn_sqrtf(dx * dx + dy * dy + dz * dz);
        if (dist < mind) {  // first-minimum semantics of jnp.argmin
            mind = dist;
            index = k;
        }
    }

    float mask = (ratio[index] <= rmin) ? 255.0f : 0.0f;
    if (!isfinite(mind)) mind = 0.0f;  // last-resort finiteness guard

    out[p] = mask;
    out[HWPIX + p] = mind;
}

extern "C" void kernel_launch(void* const* d_in, const int* in_sizes, int n_in,
                              void* d_out, int out_size, void* d_ws, size_t ws_size,
                              hipStream_t stream) {
    const float* frames = (const float*)d_in[0];
    const float* frame  = (const float*)d_in[1];
    const int*   n_iter = (const int*)d_in[2];
    float* out = (float*)d_out;

    const int threads = 64;
    const int blocks = (HWPIX + threads - 1) / threads;  // 4800 blocks
    gmm_fit_process_kernel<<<blocks, threads, 0, stream>>>(frames, frame, n_iter, out);
}

// Round 5
// 25.173 us; speedup vs baseline: 3.2800x; 1.1810x over previous
//
#include <hip/hip_runtime.h>
#include <math.h>

#define KC 3
#define NF 8
#define HH 480
#define WW 640
#define HWPIX (HH * WW)
#define NPAIR (HWPIX / 2)   // 153600 pixel-pairs, 2 px per thread

typedef float v2f __attribute__((ext_vector_type(2)));

__device__ __forceinline__ float frcp(float x) { return __builtin_amdgcn_rcpf(x); }
__device__ __forceinline__ float fexp2(float x) { return __builtin_amdgcn_exp2f(x); }
__device__ __forceinline__ v2f rcp2(v2f x) { return (v2f){frcp(x.x), frcp(x.y)}; }
__device__ __forceinline__ v2f exp2v(v2f x) { return (v2f){fexp2(x.x), fexp2(x.y)}; }
__device__ __forceinline__ v2f max2(v2f a, float b) { return (v2f){fmaxf(a.x, b), fmaxf(a.y, b)}; }
__device__ __forceinline__ v2f min2(v2f a, v2f b) { return (v2f){fminf(a.x, b.x), fminf(a.y, b.y)}; }
__device__ __forceinline__ v2f v2(float s) { return (v2f){s, s}; }

__global__ __launch_bounds__(64) void gmm_fit_process_kernel(
    const float* __restrict__ frames,   // [N,H,W,3]
    const float* __restrict__ frame,    // [H,W,3]
    const int* __restrict__ n_iter_p,
    float* __restrict__ out)            // [2,H,W]
{
    const int pp = blockIdx.x * blockDim.x + threadIdx.x;  // pixel-pair index
    if (pp >= NPAIR) return;
    const int n_iter = *n_iter_p;

    // ---- load 8 samples x 2 pixels (6 contiguous floats per frame) ----
    v2f X[NF][3];
    v2f X2[NF];
#pragma unroll
    for (int n = 0; n < NF; ++n) {
        const float* src = frames + (size_t)n * (HWPIX * 3) + (size_t)pp * 6;
        const float a0 = src[0], a1 = src[1], a2 = src[2];
        const float a3 = src[3], a4 = src[4], a5 = src[5];
        X[n][0] = (v2f){a0, a3};
        X[n][1] = (v2f){a1, a4};
        X[n][2] = (v2f){a2, a5};
        X2[n] = X[n][0] * X[n][0] + X[n][1] * X[n][1] + X[n][2] * X[n][2];
    }

    // ---- init GMM state ----
    v2f mean[KC][3], dev[KC], weight[KC];
#pragma unroll
    for (int k = 0; k < KC; ++k) {
        const float m0 = (float)(k + 1) / 4.0f;
        mean[k][0] = v2(m0); mean[k][1] = v2(m0); mean[k][2] = v2(m0);
        dev[k] = v2(1.0f);
        weight[k] = v2(1.0f / 3.0f);
    }

    const float INV_NORM = 0.06349363593424097f;  // 1/sqrt((2*pi)^3)
    const float L2E = 1.4426950408889634f;        // log2(e)
    const float DEV_FLOOR = 1e-12f;
    const float S_FLOOR = 1e-20f;

    for (int it = 0; it < n_iter; ++it) {
        // per-component constants: base-2 exponent e = A*X2 + B + C*dot(m,X)
        v2f A[KC], B[KC], C[KC], c[KC];
#pragma unroll
        for (int k = 0; k < KC; ++k) {
            const v2f invd = rcp2(max2(dev[k], DEV_FLOOR));
            const v2f a2v = v2(-0.5f * L2E) * invd * invd;
            const v2f m2 = mean[k][0] * mean[k][0] + mean[k][1] * mean[k][1]
                         + mean[k][2] * mean[k][2];
            A[k] = a2v;
            B[k] = a2v * m2;
            C[k] = v2(-2.0f) * a2v;
            c[k] = weight[k] * v2(INV_NORM) * invd;
        }

        v2f rs[KC], mx[KC], my[KC], mz[KC], acc2[KC];
#pragma unroll
        for (int k = 0; k < KC; ++k) {
            rs[k] = v2(0.0f); mx[k] = v2(0.0f); my[k] = v2(0.0f);
            mz[k] = v2(0.0f); acc2[k] = v2(0.0f);
        }

#pragma unroll
        for (int n = 0; n < NF; ++n) {
            v2f r[KC], s = v2(0.0f);
#pragma unroll
            for (int k = 0; k < KC; ++k) {
                const v2f t = mean[k][0] * X[n][0] + mean[k][1] * X[n][1]
                            + mean[k][2] * X[n][2];
                v2f e = A[k] * X2[n] + B[k];
                e = C[k] * t + e;
                r[k] = c[k] * exp2v(e);
                s += r[k];
            }
            const v2f sinv = (v2f){ (s.x > S_FLOOR) ? frcp(s.x) : 0.0f,
                                    (s.y > S_FLOOR) ? frcp(s.y) : 0.0f };
#pragma unroll
            for (int k = 0; k < KC; ++k) {
                const v2f rk = r[k] * sinv;
                rs[k] += rk;
                mx[k] += rk * X[n][0];
                my[k] += rk * X[n][1];
                mz[k] += rk * X[n][2];
                acc2[k] += rk * X2[n];
            }
        }

        // branchless M-step finalize (per-component select on starvation)
#pragma unroll
        for (int k = 0; k < KC; ++k) {
            const v2f invrs = rcp2(rs[k]);           // may be inf; discarded by select
            const v2f nm0 = mx[k] * invrs;
            const v2f nm1 = my[k] * invrs;
            const v2f nm2 = mz[k] * invrs;
            const v2f mm2 = nm0 * nm0 + nm1 * nm1 + nm2 * nm2;
            const v2f ndev = acc2[k] * invrs - mm2;  // Koenig identity
            const bool ok0 = rs[k].x > S_FLOOR;
            const bool ok1 = rs[k].y > S_FLOOR;
            mean[k][0] = (v2f){ ok0 ? nm0.x : mean[k][0].x, ok1 ? nm0.y : mean[k][0].y };
            mean[k][1] = (v2f){ ok0 ? nm1.x : mean[k][1].x, ok1 ? nm1.y : mean[k][1].y };
            mean[k][2] = (v2f){ ok0 ? nm2.x : mean[k][2].x, ok1 ? nm2.y : mean[k][2].y };
            dev[k]     = (v2f){ ok0 ? ndev.x : dev[k].x,   ok1 ? ndev.y : dev[k].y };
            weight[k] = rs[k] * v2(0.125f);          // rs/N — exact reference semantics
        }
    }

    // ---- fg ratio ----
    v2f ratio[KC];
    v2f rmin = v2(3.402823466e+38f);
#pragma unroll
    for (int k = 0; k < KC; ++k) {
        ratio[k] = weight[k] * rcp2(max2(dev[k], DEV_FLOOR));
        rmin = min2(rmin, ratio[k]);
    }

    // ---- process test frame (2 pixels) ----
    const float* fsrc = frame + (size_t)pp * 6;
    const float f0 = fsrc[0], f1 = fsrc[1], f2 = fsrc[2];
    const float f3 = fsrc[3], f4 = fsrc[4], f5 = fsrc[5];
    const v2f fx = (v2f){f0, f3}, fy = (v2f){f1, f4}, fz = (v2f){f2, f5};

    v2f dist[KC];
#pragma unroll
    for (int k = 0; k < KC; ++k) {
        const v2f dx = fx - mean[k][0];
        const v2f dy = fy - mean[k][1];
        const v2f dz = fz - mean[k][2];
        const v2f d2 = dx * dx + dy * dy + dz * dz;
        dist[k] = (v2f){ __builtin_amdgcn_sqrtf(d2.x), __builtin_amdgcn_sqrtf(d2.y) };
    }

    float maskv[2], mindv[2];
#pragma unroll
    for (int cmp = 0; cmp < 2; ++cmp) {
        float mind = 3.402823466e+38f;
        int index = 0;
#pragma unroll
        for (int k = 0; k < KC; ++k) {
            const float d = (cmp == 0) ? dist[k].x : dist[k].y;
            if (d < mind) { mind = d; index = k; }  // first-min (jnp.argmin)
        }
        const float rat  = (cmp == 0) ? ((index == 0) ? ratio[0].x : (index == 1) ? ratio[1].x : ratio[2].x)
                                      : ((index == 0) ? ratio[0].y : (index == 1) ? ratio[1].y : ratio[2].y);
        const float rmn  = (cmp == 0) ? rmin.x : rmin.y;
        maskv[cmp] = (rat <= rmn) ? 255.0f : 0.0f;
        mindv[cmp] = isfinite(mind) ? mind : 0.0f;
    }

    // adjacent-pixel outputs: 8B vector stores
    *reinterpret_cast<v2f*>(out + (size_t)pp * 2)          = (v2f){maskv[0], maskv[1]};
    *reinterpret_cast<v2f*>(out + HWPIX + (size_t)pp * 2)  = (v2f){mindv[0], mindv[1]};
}

extern "C" void kernel_launch(void* const* d_in, const int* in_sizes, int n_in,
                              void* d_out, int out_size, void* d_ws, size_t ws_size,
                              hipStream_t stream) {
    const float* frames = (const float*)d_in[0];
    const float* frame  = (const float*)d_in[1];
    const int*   n_iter = (const int*)d_in[2];
    float* out = (float*)d_out;

    const int threads = 64;
    const int blocks = (NPAIR + threads - 1) / threads;  // 2400 blocks
    gmm_fit_process_kernel<<<blocks, threads, 0, stream>>>(frames, frame, n_iter, out);
}

// Round 6
// 23.828 us; speedup vs baseline: 3.4652x; 1.0565x over previous
//
#include <hip/hip_runtime.h>
#include <math.h>

#define KC 3
#define NF 8
#define NPJ 4              // sample pairs (NF/2)
#define HH 480
#define WW 640
#define HWPIX (HH * WW)
#define FSTRIDE (HWPIX * 3)

typedef float v2f __attribute__((ext_vector_type(2)));

__device__ __forceinline__ float frcp(float x) { return __builtin_amdgcn_rcpf(x); }
__device__ __forceinline__ float fexp2(float x) { return __builtin_amdgcn_exp2f(x); }
__device__ __forceinline__ v2f exp2v(v2f x) { return (v2f){fexp2(x.x), fexp2(x.y)}; }
__device__ __forceinline__ v2f v2(float s) { return (v2f){s, s}; }

__global__ __launch_bounds__(64, 4) void gmm_fit_process_kernel(
    const float* __restrict__ frames,   // [N,H,W,3]
    const float* __restrict__ frame,    // [H,W,3]
    const int* __restrict__ n_iter_p,
    float* __restrict__ out)            // [2,H,W]
{
    const int p = blockIdx.x * blockDim.x + threadIdx.x;  // one pixel per thread
    if (p >= HWPIX) return;
    const int n_iter = *n_iter_p;

    // ---- load 8 samples, packed as 4 sample-PAIRS in v2f lanes ----
    // Xp[j][c] = { X[2j][c], X[2j+1][c] }
    v2f Xp[NPJ][3], X2p[NPJ];
#pragma unroll
    for (int j = 0; j < NPJ; ++j) {
        const float* s0 = frames + (size_t)(2 * j)     * FSTRIDE + (size_t)p * 3;
        const float* s1 = frames + (size_t)(2 * j + 1) * FSTRIDE + (size_t)p * 3;
        Xp[j][0] = (v2f){s0[0], s1[0]};
        Xp[j][1] = (v2f){s0[1], s1[1]};
        Xp[j][2] = (v2f){s0[2], s1[2]};
        X2p[j] = Xp[j][0] * Xp[j][0] + Xp[j][1] * Xp[j][1] + Xp[j][2] * Xp[j][2];
    }

    // ---- scalar per-pixel GMM state ----
    float mean[KC][3], dev[KC], weight[KC];
#pragma unroll
    for (int k = 0; k < KC; ++k) {
        const float m0 = (float)(k + 1) / 4.0f;
        mean[k][0] = m0; mean[k][1] = m0; mean[k][2] = m0;
        dev[k] = 1.0f;
        weight[k] = 1.0f / 3.0f;
    }

    const float INV_NORM = 0.06349363593424097f;  // 1/sqrt((2*pi)^3)
    const float L2E = 1.4426950408889634f;        // log2(e)
    const float DEV_FLOOR = 1e-12f;
    const float S_FLOOR = 1e-20f;

    for (int it = 0; it < n_iter; ++it) {
        // scalar per-component constants (3 rcp / iter):
        // base-2 exponent e = A*||X||^2 + B + C*dot(mean,X)
        float A[KC], B[KC], C[KC], cc[KC];
#pragma unroll
        for (int k = 0; k < KC; ++k) {
            const float invd = frcp(fmaxf(dev[k], DEV_FLOOR));
            const float a2 = -0.5f * L2E * invd * invd;
            const float m2 = mean[k][0] * mean[k][0] + mean[k][1] * mean[k][1]
                           + mean[k][2] * mean[k][2];
            A[k] = a2;
            B[k] = a2 * m2;
            C[k] = -2.0f * a2;
            cc[k] = weight[k] * INV_NORM * invd;
        }

        // packed accumulators over sample pairs
        v2f rs[KC], mx[KC], my[KC], mz[KC], ac2[KC];
#pragma unroll
        for (int k = 0; k < KC; ++k) {
            rs[k] = v2(0.0f); mx[k] = v2(0.0f); my[k] = v2(0.0f);
            mz[k] = v2(0.0f); ac2[k] = v2(0.0f);
        }

#pragma unroll
        for (int j = 0; j < NPJ; ++j) {
            v2f r[KC], s = v2(0.0f);
#pragma unroll
            for (int k = 0; k < KC; ++k) {
                const v2f t = v2(mean[k][0]) * Xp[j][0]
                            + v2(mean[k][1]) * Xp[j][1]
                            + v2(mean[k][2]) * Xp[j][2];
                v2f e = v2(A[k]) * X2p[j] + v2(B[k]);
                e = v2(C[k]) * t + e;
                r[k] = v2(cc[k]) * exp2v(e);
                s += r[k];
            }
            const v2f sinv = (v2f){ (s.x > S_FLOOR) ? frcp(s.x) : 0.0f,
                                    (s.y > S_FLOOR) ? frcp(s.y) : 0.0f };
#pragma unroll
            for (int k = 0; k < KC; ++k) {
                const v2f rk = r[k] * sinv;
                rs[k]  += rk;
                mx[k]  += rk * Xp[j][0];
                my[k]  += rk * Xp[j][1];
                mz[k]  += rk * Xp[j][2];
                ac2[k] += rk * X2p[j];
            }
        }

        // scalar M-step finalize (horizontal add over the pair lanes)
#pragma unroll
        for (int k = 0; k < KC; ++k) {
            const float rsk = rs[k].x + rs[k].y;
            const float mxs = mx[k].x + mx[k].y;
            const float mys = my[k].x + my[k].y;
            const float mzs = mz[k].x + mz[k].y;
            const float a2s = ac2[k].x + ac2[k].y;
            const float invrs = frcp(rsk);            // garbage if starved; selected away
            const float nm0 = mxs * invrs, nm1 = mys * invrs, nm2 = mzs * invrs;
            const float mm2 = nm0 * nm0 + nm1 * nm1 + nm2 * nm2;
            const float ndev = a2s * invrs - mm2;     // Koenig identity
            const bool ok = rsk > S_FLOOR;
            mean[k][0] = ok ? nm0 : mean[k][0];
            mean[k][1] = ok ? nm1 : mean[k][1];
            mean[k][2] = ok ? nm2 : mean[k][2];
            dev[k]     = ok ? ndev : dev[k];
            weight[k]  = rsk * 0.125f;                // rs/N — reference semantics
        }
    }

    // ---- fg ratio ----
    float ratio[KC];
    float rmin = 3.402823466e+38f;
#pragma unroll
    for (int k = 0; k < KC; ++k) {
        ratio[k] = weight[k] * frcp(fmaxf(dev[k], DEV_FLOOR));
        rmin = fminf(rmin, ratio[k]);
    }

    // ---- process the single test frame ----
    const float fx = frame[(size_t)p * 3 + 0];
    const float fy = frame[(size_t)p * 3 + 1];
    const float fz = frame[(size_t)p * 3 + 2];

    float mind = 3.402823466e+38f;
    int index = 0;
#pragma unroll
    for (int k = 0; k < KC; ++k) {
        const float dx = fx - mean[k][0];
        const float dy = fy - mean[k][1];
        const float dz = fz - mean[k][2];
        const float dist = __builtin_amdgcn_sqrtf(dx * dx + dy * dy + dz * dz);
        if (dist < mind) { mind = dist; index = k; }  // first-min (jnp.argmin)
    }

    const float mask = (ratio[index] <= rmin) ? 255.0f : 0.0f;
    out[p] = mask;
    out[HWPIX + p] = isfinite(mind) ? mind : 0.0f;
}

extern "C" void kernel_launch(void* const* d_in, const int* in_sizes, int n_in,
                              void* d_out, int out_size, void* d_ws, size_t ws_size,
                              hipStream_t stream) {
    const float* frames = (const float*)d_in[0];
    const float* frame  = (const float*)d_in[1];
    const int*   n_iter = (const int*)d_in[2];
    float* out = (float*)d_out;

    const int threads = 64;
    const int blocks = (HWPIX + threads - 1) / threads;  // 4800 blocks = 4800 waves
    gmm_fit_process_kernel<<<blocks, threads, 0, stream>>>(frames, frame, n_iter, out);
}